// Round 1
// baseline (39134.918 us; speedup 1.0000x reference)
//
#include <hip/hip_runtime.h>
#include <stdint.h>
#include <stddef.h>

// PowerLawLayer RNN, MI355X persistent-kernel design.
//
//   B=64, T=1024, I=256, H=512, fp32 (no fp32 MFMA on CDNA4 -> vector FMA).
//   gates = x_t @ W_ih^T + h @ W_hh^T + bias ; r,o = sigmoid ; g = tanh
//   k' = r(t-eps)+(1-r)k ; f = ((t-k'+eps)/(t-k'+1))^p ; c' = f c + (1-f) g
//   h' = o tanh(c')
//
// Decomposition: 256 wgs x 1024 thr, 1 wg/CU.
//   wg = (hidden slice of 64 j's) x (batch pair).  8 peer wgs cover one
//   batch pair; they exchange 64-float h slices per step through a global
//   ping-pong buffer with device(agent)-scope atomics (correct under any
//   XCD placement; blockIdx swizzle co-locates peers on one XCD for speed).
//   Weights are REGISTER-RESIDENT: lane l <-> hidden j0+l (rows j, j+512,
//   j+1024), wave w <-> k-chunk (32 h-k + 16 x-k) => 144 floats/thread,
//   loaded once, reused 1024 steps. h/x are read via LDS same-address
//   broadcast ds_read_b128 (1 read : 12 FMA).
//
// Workspace: hbuf[2][64][512] f32 (ping-pong) + ctr[32] u32 = 262,272 B.

#define Hh   512
#define Tt   1024
#define Bb   64
#define II   256
#define EPSc 0.001f
#define PV   0.2f
#define NPEER 8

__global__ __launch_bounds__(1024) void plr_init(float* hbuf, unsigned* ctr) {
  int idx = blockIdx.x * blockDim.x + threadIdx.x;
  if (idx < Bb * Hh) hbuf[idx] = 0.0f;        // h(0) = 0 in buffer 0
  if (idx < 32) ctr[idx] = 0u;                // barrier counters
}

__global__ __launch_bounds__(1024) void plr_main(
    const float* __restrict__ x,    // [B, T, I]
    const float* __restrict__ Wih,  // [3H, I]
    const float* __restrict__ Whh,  // [3H, H]
    const float* __restrict__ bias, // [3H]
    float* __restrict__ out,        // [B,T,H] ++ h_f ++ c_f ++ k_f
    float* hbuf,                    // [2][B][H]
    unsigned* ctr)                  // [32]
{
  __shared__ float h_tile[2 * Hh];           // [bl][k]
  __shared__ float x_tile[2 * II];           // [bl][k]
  __shared__ float part[16 * 2 * 3 * 64];    // [wave][bl][gate][lane] 24KB

  const int tid = threadIdx.x;
  const int w = tid >> 6;          // wave 0..15  (k-chunk)
  const int l = tid & 63;          // lane 0..63  (hidden offset)
  const int bid = blockIdx.x;
  // peers (same batch group g) share bid % 8 -> same XCD under round-robin
  const int g  = (bid & 7) + 8 * (bid >> 6); // batch group 0..31
  const int s  = (bid >> 3) & 7;             // hidden slice 0..7
  const int j0 = s * 64;
  const int b0 = g * 2;

  // ---- one-time: weights into registers -------------------------------
  float whh[3][32];
  float wih[3][16];
#pragma unroll
  for (int gi = 0; gi < 3; ++gi) {
    const int row = gi * Hh + j0 + l;
    const float4* ph = (const float4*)(Whh + (size_t)row * Hh + w * 32);
#pragma unroll
    for (int i = 0; i < 8; ++i) {
      float4 v = ph[i];
      whh[gi][4*i+0] = v.x; whh[gi][4*i+1] = v.y;
      whh[gi][4*i+2] = v.z; whh[gi][4*i+3] = v.w;
    }
    const float4* pi = (const float4*)(Wih + (size_t)row * II + w * 16);
#pragma unroll
    for (int i = 0; i < 4; ++i) {
      float4 v = pi[i];
      wih[gi][4*i+0] = v.x; wih[gi][4*i+1] = v.y;
      wih[gi][4*i+2] = v.z; wih[gi][4*i+3] = v.w;
    }
  }

  // ---- updater state (threads 0..127: bl = tid>>6, j = j0 + (tid&63)) --
  float c_st = 0.0f, k_st = -1.0f;
  float bia0 = 0.f, bia1 = 0.f, bia2 = 0.f;
  if (tid < 128) {
    const int jl = tid & 63;
    bia0 = bias[0 * Hh + j0 + jl];
    bia1 = bias[1 * Hh + j0 + jl];
    bia2 = bias[2 * Hh + j0 + jl];
  }

  bool broken = false;  // bounded-spin escape (never taken when co-resident)

  for (int t = 0; t < Tt; ++t) {
    // ---- stage h(t) (LLC-coherent) and x_t into LDS --------------------
    {
      const int bl = tid >> 9, k = tid & 511;
      float hv = __hip_atomic_load(
          hbuf + (size_t)(t & 1) * Bb * Hh + (size_t)(b0 + bl) * Hh + k,
          __ATOMIC_RELAXED, __HIP_MEMORY_SCOPE_AGENT);
      h_tile[bl * Hh + k] = hv;
      if (tid < 512) {
        const int bl2 = tid >> 8, k2 = tid & 255;
        x_tile[bl2 * II + k2] = x[((size_t)(b0 + bl2) * Tt + t) * II + k2];
      }
    }
    __syncthreads();

    // ---- gemv: 144 FMA per lane per batch, broadcast LDS reads ---------
#pragma unroll
    for (int bl = 0; bl < 2; ++bl) {
      const float4* h4 = (const float4*)(h_tile + bl * Hh) + w * 8;
      const float4* x4 = (const float4*)(x_tile + bl * II) + w * 4;
      float a0 = 0.f, a1 = 0.f, a2 = 0.f;
#pragma unroll
      for (int i = 0; i < 8; ++i) {
        float4 hv = h4[i];
        a0 = fmaf(whh[0][4*i+0], hv.x, a0); a0 = fmaf(whh[0][4*i+1], hv.y, a0);
        a0 = fmaf(whh[0][4*i+2], hv.z, a0); a0 = fmaf(whh[0][4*i+3], hv.w, a0);
        a1 = fmaf(whh[1][4*i+0], hv.x, a1); a1 = fmaf(whh[1][4*i+1], hv.y, a1);
        a1 = fmaf(whh[1][4*i+2], hv.z, a1); a1 = fmaf(whh[1][4*i+3], hv.w, a1);
        a2 = fmaf(whh[2][4*i+0], hv.x, a2); a2 = fmaf(whh[2][4*i+1], hv.y, a2);
        a2 = fmaf(whh[2][4*i+2], hv.z, a2); a2 = fmaf(whh[2][4*i+3], hv.w, a2);
      }
#pragma unroll
      for (int i = 0; i < 4; ++i) {
        float4 xv = x4[i];
        a0 = fmaf(wih[0][4*i+0], xv.x, a0); a0 = fmaf(wih[0][4*i+1], xv.y, a0);
        a0 = fmaf(wih[0][4*i+2], xv.z, a0); a0 = fmaf(wih[0][4*i+3], xv.w, a0);
        a1 = fmaf(wih[1][4*i+0], xv.x, a1); a1 = fmaf(wih[1][4*i+1], xv.y, a1);
        a1 = fmaf(wih[1][4*i+2], xv.z, a1); a1 = fmaf(wih[1][4*i+3], xv.w, a1);
        a2 = fmaf(wih[2][4*i+0], xv.x, a2); a2 = fmaf(wih[2][4*i+1], xv.y, a2);
        a2 = fmaf(wih[2][4*i+2], xv.z, a2); a2 = fmaf(wih[2][4*i+3], xv.w, a2);
      }
      part[((w * 2 + bl) * 3 + 0) * 64 + l] = a0;
      part[((w * 2 + bl) * 3 + 1) * 64 + l] = a1;
      part[((w * 2 + bl) * 3 + 2) * 64 + l] = a2;
    }
    __syncthreads();

    // ---- reduce + elementwise + store (threads 0..127) -----------------
    if (tid < 128) {
      const int bl = tid >> 6, jl = tid & 63;
      float s0 = bia0, s1 = bia1, s2 = bia2;
#pragma unroll
      for (int ww = 0; ww < 16; ++ww) {
        s0 += part[((ww * 2 + bl) * 3 + 0) * 64 + jl];
        s1 += part[((ww * 2 + bl) * 3 + 1) * 64 + jl];
        s2 += part[((ww * 2 + bl) * 3 + 2) * 64 + jl];
      }
      const float tf = (float)t;
      const float r  = 1.0f / (1.0f + __expf(-s0));
      const float o  = 1.0f / (1.0f + __expf(-s1));
      const float gg = 1.0f - 2.0f / (1.0f + __expf(2.0f * s2));
      const float kn = r * (tf - EPSc) + (1.0f - r) * k_st;
      const float d  = tf - kn;
      const float f  = __expf(PV * __logf((d + EPSc) / (d + 1.0f)));
      const float cn = f * c_st + (1.0f - f) * gg;
      const float hn = o * (1.0f - 2.0f / (1.0f + __expf(2.0f * cn)));
      c_st = cn; k_st = kn;
      const int b = b0 + bl, j = j0 + jl;
      out[((size_t)b * Tt + t) * Hh + j] = hn;
      __hip_atomic_store(
          hbuf + (size_t)((t + 1) & 1) * Bb * Hh + (size_t)b * Hh + j, hn,
          __ATOMIC_RELAXED, __HIP_MEMORY_SCOPE_AGENT);
      if (t == Tt - 1) {
        const size_t base = (size_t)Bb * Tt * Hh;
        out[base + 0 * Bb * Hh + (size_t)b * Hh + j] = hn;  // h_f
        out[base + 1 * Bb * Hh + (size_t)b * Hh + j] = cn;  // c_f
        out[base + 2 * Bb * Hh + (size_t)b * Hh + j] = kn;  // k_f
      }
    }

    // ---- 8-peer barrier (skip after last step) -------------------------
    if (t < Tt - 1) {
      __syncthreads();  // drains updater global stores (vmcnt) before signal
      if (tid == 0) {
        __hip_atomic_fetch_add(ctr + g, 1u, __ATOMIC_RELEASE,
                               __HIP_MEMORY_SCOPE_AGENT);
        if (!broken) {
          const unsigned target = (unsigned)NPEER * (unsigned)(t + 1);
          int it = 0;
          while (__hip_atomic_load(ctr + g, __ATOMIC_ACQUIRE,
                                   __HIP_MEMORY_SCOPE_AGENT) < target) {
            __builtin_amdgcn_s_sleep(2);
            if (++it > (1 << 22)) { broken = true; break; }
          }
        }
      }
      __syncthreads();  // all threads see acquire via tid0 + barrier
    }
  }
}

extern "C" void kernel_launch(void* const* d_in, const int* in_sizes, int n_in,
                              void* d_out, int out_size, void* d_ws, size_t ws_size,
                              hipStream_t stream) {
  const float* x    = (const float*)d_in[0];
  const float* Wih  = (const float*)d_in[1];
  const float* Whh  = (const float*)d_in[2];
  const float* bias = (const float*)d_in[3];
  float* out = (float*)d_out;

  float*    hbuf = (float*)d_ws;                                  // 2*64*512 f32
  unsigned* ctr  = (unsigned*)((char*)d_ws + 2 * Bb * Hh * sizeof(float));

  plr_init<<<32, 1024, 0, stream>>>(hbuf, ctr);
  plr_main<<<256, 1024, 0, stream>>>(x, Wih, Whh, bias, out, hbuf, ctr);
}